// Round 8
// baseline (2432.440 us; speedup 1.0000x reference)
//
#include <hip/hip_runtime.h>
#include <hip/hip_bf16.h>

#define UNIT 20
#define HID 36
#define G4 144      // 4*HID
#define INW 80      // 4*UNIT
#define NCLS 3
#define TT 40960
#define SS 2048     // TT/UNIT
#define BB 512
#define CHK 128
#define NCHK (SS/CHK)   // 16
#define NPROD 384
#define NCONS 128
#define PAD 16

typedef float v2f __attribute__((ext_vector_type(2)));

__device__ __forceinline__ float exp2_hw(float x){ float r; asm("v_exp_f32 %0, %1" : "=v"(r) : "v"(x)); return r; }
__device__ __forceinline__ float rcp_hw(float x){ float r; asm("v_rcp_f32 %0, %1" : "=v"(r) : "v"(x)); return r; }
__device__ __forceinline__ float sigm_hw(float x){ return rcp_hw(1.f + exp2_hw(-1.4426950408889634f * x)); }
__device__ __forceinline__ float tanh_hw(float x){ return 1.f - 2.f * rcp_hw(1.f + exp2_hw(2.8853900817779268f * x)); }
__device__ __forceinline__ float rl(float v, int l){
    return __uint_as_float(__builtin_amdgcn_readlane(__float_as_uint(v), l));
}

__global__ void init_flags(int* f){ f[threadIdx.x] = 0; }

// ============ persistent producer/consumer, correctly sized ============
// Producers: blocks 0..383 (192 thr), k-major over 8192 (chunk,batch) units.
// Consumers: blocks 384..511 (4 waves = 4 batches), barrier-free recurrence.
// xw layout: [step][batch][4*u + {i,f,g,o}]  (gate-interleaved float4 per unit)
__global__ __launch_bounds__(256)
void lstm_pc2(const float* __restrict__ x, const float* __restrict__ h0,
              const float* __restrict__ c0, const float* __restrict__ W_ih,
              const float* __restrict__ W_hh, const float* __restrict__ b_ih,
              const float* __restrict__ b_hh, const float* __restrict__ fc1_w,
              const float* __restrict__ fc1_b, const float* __restrict__ fc2_w,
              const float* __restrict__ fc2_b, float* __restrict__ out,
              int* __restrict__ flags, float* __restrict__ xw)
{
    const int tid = threadIdx.x;

    if (blockIdx.x < NPROD) {
        if (tid >= 192) return;               // whole wave 3 exits before any barrier
        __shared__ __align__(16) float xin[16][INW];

        const bool act = (tid < 144);
        const int pr   = act ? (tid % 72) : 0;
        const int slot = act ? (tid / 72) : 0;
        const int uo   = pr % 36;
        const int goff = 4*uo + ((pr < 36) ? 0 : 1);   // i/f slot; +2 gives g/o

        v2f wpk[INW]; v2f bias2 = {0.f, 0.f};
        if (act) {
            const float* w0 = W_ih + (size_t)pr * INW;
            const float* w1 = W_ih + (size_t)(pr + 72) * INW;
            #pragma unroll
            for (int q = 0; q < INW; ++q) wpk[q] = (v2f){w0[q], w1[q]};
            bias2 = (v2f){b_ih[pr] + b_hh[pr], b_ih[pr+72] + b_hh[pr+72]};
        }

        for (int u = blockIdx.x; u < NCHK*BB; u += NPROD) {
            const int k = u >> 9;             // u / 512  (k-major)
            const int b = u & 511;
            const float* xb = x + (size_t)b * 4 * TT;

            for (int sub = 0; sub < CHK; sub += 16) {
                const int sg = k*CHK + sub;
                __syncthreads();              // xin reuse guard
                for (int j = tid; j < 320; j += 192) {
                    int c = j / 80, q = j - c*80;
                    float4 v = ((const float4*)(xb + (size_t)c*TT + (size_t)sg*UNIT))[q];
                    int e = q*4; int sl = e / UNIT, uu = e - sl*UNIT;
                    *(float4*)&xin[sl][c*UNIT + uu] = v;
                }
                __syncthreads();
                if (act) {
                    for (int si = slot; si < 16; si += 2) {
                        const float4* xv = (const float4*)xin[si];
                        v2f a0 = bias2, a1 = {0.f,0.f}, a2 = {0.f,0.f}, a3 = {0.f,0.f};
                        #pragma unroll
                        for (int q = 0; q < 20; ++q) {
                            float4 v = xv[q];
                            a0 += v.x * wpk[4*q+0];
                            a1 += v.y * wpk[4*q+1];
                            a2 += v.z * wpk[4*q+2];
                            a3 += v.w * wpk[4*q+3];
                        }
                        v2f res = (a0 + a1) + (a2 + a3);
                        size_t o = ((size_t)(sg + si) * BB + b) * G4;
                        xw[o + goff]     = res[0];
                        xw[o + goff + 2] = res[1];
                    }
                }
            }
            __threadfence();
            __syncthreads();
            if (tid == 0)
                __hip_atomic_fetch_add(&flags[k], 1, __ATOMIC_RELEASE, __HIP_MEMORY_SCOPE_AGENT);
        }
    } else {
        // ---------------- consumer: 1 wave per batch ----------------
        const int wid  = tid >> 6;
        const int lane = tid & 63;
        const int b    = (blockIdx.x - NPROD) * 4 + wid;
        const int jj   = (lane < HID) ? lane : 0;

        v2f wif[HID], wgo[HID];
        #pragma unroll
        for (int q = 0; q < HID; ++q) {
            wif[q] = (v2f){ W_hh[(size_t)jj*HID + q],         W_hh[(size_t)(HID+jj)*HID + q] };
            wgo[q] = (v2f){ W_hh[(size_t)(2*HID+jj)*HID + q], W_hh[(size_t)(3*HID+jj)*HID + q] };
        }

        float hval = h0[b*HID + jj];
        float cval = c0[b*HID + jj];
        float hs[HID];
        #pragma unroll
        for (int q = 0; q < HID; ++q) hs[q] = rl(hval, q);

        const float*  xp     = xw + (size_t)b * G4 + 4*jj;
        const size_t  STRIDE = (size_t)BB * G4;

        float4 qa[8], qb[8];

#define LOADBANK(dst, base) { \
    _Pragma("unroll") for (int u = 0; u < 8; ++u) \
        dst[u] = *(const float4*)(xp + (size_t)((base) + u) * STRIDE); }

#define DOSTEP(bk, u) { \
    v2f aifA = { bk[u].x, bk[u].y }, aifB = {0.f,0.f}; \
    v2f agoA = { bk[u].z, bk[u].w }, agoB = {0.f,0.f}; \
    _Pragma("unroll") for (int q = 0; q < HID; q += 2) { \
        aifA += hs[q]   * wif[q]; \
        agoA += hs[q]   * wgo[q]; \
        aifB += hs[q+1] * wif[q+1]; \
        agoB += hs[q+1] * wgo[q+1]; \
    } \
    v2f aif = aifA + aifB, ago = agoA + agoB; \
    float gi = sigm_hw(aif[0]), gf = sigm_hw(aif[1]); \
    float gg = tanh_hw(ago[0]), go = sigm_hw(ago[1]); \
    cval = gf * cval + gi * gg; \
    hval = go * tanh_hw(cval); \
    _Pragma("unroll") for (int q = 0; q < HID; ++q) hs[q] = rl(hval, q); }

        for (int k = 0; k < NCHK; ++k) {
            while (__hip_atomic_load(&flags[k], __ATOMIC_RELAXED, __HIP_MEMORY_SCOPE_AGENT) < BB)
                __builtin_amdgcn_s_sleep(2);
            (void)__hip_atomic_load(&flags[k], __ATOMIC_ACQUIRE, __HIP_MEMORY_SCOPE_AGENT);

            const int base = k * CHK;
            LOADBANK(qa, base);
            for (int s8 = 0; s8 < CHK; s8 += 16) {
                LOADBANK(qb, base + s8 + 8);
                DOSTEP(qa,0) DOSTEP(qa,1) DOSTEP(qa,2) DOSTEP(qa,3)
                DOSTEP(qa,4) DOSTEP(qa,5) DOSTEP(qa,6) DOSTEP(qa,7)
                if (s8 < CHK - 16) LOADBANK(qa, base + s8 + 16);
                DOSTEP(qb,0) DOSTEP(qb,1) DOSTEP(qb,2) DOSTEP(qb,3)
                DOSTEP(qb,4) DOSTEP(qb,5) DOSTEP(qb,6) DOSTEP(qb,7)
            }
        }
#undef LOADBANK
#undef DOSTEP

        float a1 = 0.f;
        if (lane < 16) {
            a1 = fc1_b[lane];
            #pragma unroll
            for (int q = 0; q < HID; ++q) a1 += hs[q] * fc1_w[lane*HID + q];
            a1 = fmaxf(a1, 0.f);
        }
        float f1[16];
        #pragma unroll
        for (int q = 0; q < 16; ++q) f1[q] = rl(a1, q);
        if (lane < NCLS) {
            float a2 = fc2_b[lane];
            #pragma unroll
            for (int q = 0; q < 16; ++q) a2 += f1[q] * fc2_w[lane*16 + q];
            out[b*NCLS + lane] = a2;
        }
    }
}

// ============ fallback serial path (interleaved layout) ============
__global__ __launch_bounds__(192)
void lstm_proj2(const float* __restrict__ x, const float* __restrict__ W_ih,
                const float* __restrict__ b_ih, const float* __restrict__ b_hh,
                float* __restrict__ xw, int s0, int cnt, int nseq)
{
    const int bid = blockIdx.x;
    const int r   = bid % nseq;
    const int b   = bid / nseq;
    const int t   = threadIdx.x;
    const int base_local = r * 128;
    const int mysteps = min(128, cnt - base_local);
    const bool act = (t < 144);
    const int pr   = act ? (t % 72) : 0;
    const int slot = act ? (t / 72) : 0;
    const int uo   = pr % 36;
    const int goff = 4*uo + ((pr < 36) ? 0 : 1);

    __shared__ __align__(16) float xin[16][INW];

    v2f wpk[INW]; v2f bias2 = {0.f, 0.f};
    if (act) {
        const float* w0 = W_ih + (size_t)pr * INW;
        const float* w1 = W_ih + (size_t)(pr + 72) * INW;
        #pragma unroll
        for (int q = 0; q < INW; ++q) wpk[q] = (v2f){w0[q], w1[q]};
        bias2 = (v2f){b_ih[pr] + b_hh[pr], b_ih[pr+72] + b_hh[pr+72]};
    }
    const float* xb = x + (size_t)b * 4 * TT;

    for (int sub = 0; sub < mysteps; sub += 16) {
        const int sg = s0 + base_local + sub;
        __syncthreads();
        for (int j = t; j < 320; j += 192) {
            int c = j / 80, q = j - c*80;
            float4 v = ((const float4*)(xb + (size_t)c*TT + (size_t)sg*UNIT))[q];
            int e = q*4; int sl = e / UNIT, u = e - sl*UNIT;
            *(float4*)&xin[sl][c*UNIT + u] = v;
        }
        __syncthreads();
        if (act) {
            for (int si = slot; si < 16; si += 2) {
                const float4* xv = (const float4*)xin[si];
                v2f a0 = bias2, a1 = {0.f,0.f}, a2 = {0.f,0.f}, a3 = {0.f,0.f};
                #pragma unroll
                for (int q = 0; q < 20; ++q) {
                    float4 v = xv[q];
                    a0 += v.x * wpk[4*q+0];
                    a1 += v.y * wpk[4*q+1];
                    a2 += v.z * wpk[4*q+2];
                    a3 += v.w * wpk[4*q+3];
                }
                v2f res = (a0 + a1) + (a2 + a3);
                size_t o = ((size_t)(base_local + sub + si) * BB + b) * G4;
                xw[o + goff]     = res[0];
                xw[o + goff + 2] = res[1];
            }
        }
    }
}

__global__ __launch_bounds__(256)
void lstm_recur(const float* __restrict__ xw, const float* __restrict__ h0,
                const float* __restrict__ c0, const float* __restrict__ W_hh,
                const float* __restrict__ fc1_w, const float* __restrict__ fc1_b,
                const float* __restrict__ fc2_w, const float* __restrict__ fc2_b,
                float* __restrict__ state, float* __restrict__ out, int s0, int cnt)
{
    const int wid  = threadIdx.x >> 6;
    const int lane = threadIdx.x & 63;
    const int b    = blockIdx.x * 4 + wid;
    const int jj   = (lane < HID) ? lane : 0;

    v2f wif[HID], wgo[HID];
    #pragma unroll
    for (int q = 0; q < HID; ++q) {
        wif[q] = (v2f){ W_hh[(size_t)jj*HID + q],         W_hh[(size_t)(HID+jj)*HID + q] };
        wgo[q] = (v2f){ W_hh[(size_t)(2*HID+jj)*HID + q], W_hh[(size_t)(3*HID+jj)*HID + q] };
    }

    float hval, cval;
    if (s0 == 0) { hval = h0[b*HID + jj];    cval = c0[b*HID + jj]; }
    else         { hval = state[b*HID + jj]; cval = state[BB*HID + b*HID + jj]; }

    float hs[HID];
    #pragma unroll
    for (int q = 0; q < HID; ++q) hs[q] = rl(hval, q);

    const float*  xp     = xw + (size_t)b * G4 + 4*jj;
    const size_t  STRIDE = (size_t)BB * G4;

    float4 qa[8], qb[8];

#define LOADBANK(dst, base) { \
    _Pragma("unroll") for (int u = 0; u < 8; ++u) { \
        int ss = (base) + u; \
        dst[u] = *(const float4*)(xp + (size_t)((ss < cnt) ? ss : 0) * STRIDE); \
    } }

#define DOSTEP(bk, u) { \
    v2f aifA = { bk[u].x, bk[u].y }, aifB = {0.f,0.f}; \
    v2f agoA = { bk[u].z, bk[u].w }, agoB = {0.f,0.f}; \
    _Pragma("unroll") for (int q = 0; q < HID; q += 2) { \
        aifA += hs[q]   * wif[q]; \
        agoA += hs[q]   * wgo[q]; \
        aifB += hs[q+1] * wif[q+1]; \
        agoB += hs[q+1] * wgo[q+1]; \
    } \
    v2f aif = aifA + aifB, ago = agoA + agoB; \
    float gi = sigm_hw(aif[0]), gf = sigm_hw(aif[1]); \
    float gg = tanh_hw(ago[0]), go = sigm_hw(ago[1]); \
    cval = gf * cval + gi * gg; \
    hval = go * tanh_hw(cval); \
    _Pragma("unroll") for (int q = 0; q < HID; ++q) hs[q] = rl(hval, q); }

    LOADBANK(qa, 0);
    for (int s8 = 0; s8 < cnt; s8 += 16) {
        LOADBANK(qb, s8 + 8);
        DOSTEP(qa,0) DOSTEP(qa,1) DOSTEP(qa,2) DOSTEP(qa,3)
        DOSTEP(qa,4) DOSTEP(qa,5) DOSTEP(qa,6) DOSTEP(qa,7)
        LOADBANK(qa, s8 + 16);
        DOSTEP(qb,0) DOSTEP(qb,1) DOSTEP(qb,2) DOSTEP(qb,3)
        DOSTEP(qb,4) DOSTEP(qb,5) DOSTEP(qb,6) DOSTEP(qb,7)
    }
#undef LOADBANK
#undef DOSTEP

    if (s0 + cnt == SS) {
        float a1 = 0.f;
        if (lane < 16) {
            a1 = fc1_b[lane];
            #pragma unroll
            for (int k = 0; k < HID; ++k) a1 += hs[k] * fc1_w[lane*HID + k];
            a1 = fmaxf(a1, 0.f);
        }
        float f1[16];
        #pragma unroll
        for (int k = 0; k < 16; ++k) f1[k] = rl(a1, k);
        if (lane < NCLS) {
            float a2 = fc2_b[lane];
            #pragma unroll
            for (int k = 0; k < 16; ++k) a2 += f1[k] * fc2_w[lane*16 + k];
            out[b*NCLS + lane] = a2;
        }
    } else {
        if (lane < HID) {
            state[b*HID + lane]          = hval;
            state[BB*HID + b*HID + lane] = cval;
        }
    }
}

// ---------------- fallback (R1 fused kernel) for undersized workspace ----------------
__global__ __launch_bounds__(192)
void lstm_fused(const float* __restrict__ x, const float* __restrict__ h0,
                const float* __restrict__ c0, const float* __restrict__ W_ih,
                const float* __restrict__ W_hh, const float* __restrict__ b_ih,
                const float* __restrict__ b_hh, const float* __restrict__ fc1_w,
                const float* __restrict__ fc1_b, const float* __restrict__ fc2_w,
                const float* __restrict__ fc2_b, float* __restrict__ out)
{
    const int b = blockIdx.x;
    const int t = threadIdx.x;
    __shared__ __align__(16) float xin[16][INW];
    __shared__ __align__(16) float xwl[16][G4];
    __shared__ __align__(16) float h_s[HID];
    __shared__ __align__(16) float g_s[G4];
    float wih[INW]; float whh[HID];
    float bias = 0.f, K = 0.f, Aa = 0.f, Bb = 0.f;
    if (t < G4) {
        const float4* wr = (const float4*)(W_ih + t * INW);
        #pragma unroll
        for (int i = 0; i < INW/4; ++i) { float4 v = wr[i]; wih[4*i]=v.x; wih[4*i+1]=v.y; wih[4*i+2]=v.z; wih[4*i+3]=v.w; }
        const float4* hr = (const float4*)(W_hh + t * HID);
        #pragma unroll
        for (int j = 0; j < HID/4; ++j) { float4 v = hr[j]; whh[4*j]=v.x; whh[4*j+1]=v.y; whh[4*j+2]=v.z; whh[4*j+3]=v.w; }
        bias = b_ih[t] + b_hh[t];
        const bool tnh = (t >= 2*HID && t < 3*HID);
        K  = tnh ?  2.8853900817779268f : -1.4426950408889634f;
        Aa = tnh ?  1.f : 0.f;
        Bb = tnh ? -2.f : 1.f;
    }
    float c = 0.f;
    if (t < HID) { c = c0[b*HID + t]; h_s[t] = h0[b*HID + t]; }
    __syncthreads();
    const float* xb = x + (size_t)b * 4 * TT;
    for (int ck = 0; ck < SS/16; ++ck) {
        const int base = ck * 16 * UNIT;
        for (int j = t; j < 4*16*UNIT; j += 192) {
            int chn = j / (16*UNIT); int r = j - chn*(16*UNIT);
            xin[r/UNIT][chn*UNIT + (r%UNIT)] = xb[chn*TT + base + r];
        }
        __syncthreads();
        if (t < G4) {
            for (int s = 0; s < 16; ++s) {
                const float4* xv = (const float4*)xin[s];
                float a0 = bias, a1 = 0.f, a2 = 0.f, a3 = 0.f;
                #pragma unroll
                for (int i = 0; i < INW/4; ++i) {
                    float4 v = xv[i];
                    a0 += v.x*wih[4*i]; a1 += v.y*wih[4*i+1]; a2 += v.z*wih[4*i+2]; a3 += v.w*wih[4*i+3];
                }
                xwl[s][t] = (a0+a1)+(a2+a3);
            }
        }
        __syncthreads();
        for (int s = 0; s < 16; ++s) {
            if (t < G4) {
                const float4* hv = (const float4*)h_s;
                float a0 = xwl[s][t], a1 = 0.f, a2 = 0.f, a3 = 0.f;
                #pragma unroll
                for (int j = 0; j < HID/4; ++j) {
                    float4 v = hv[j];
                    a0 += v.x*whh[4*j]; a1 += v.y*whh[4*j+1]; a2 += v.z*whh[4*j+2]; a3 += v.w*whh[4*j+3];
                }
                float acc = (a0+a1)+(a2+a3);
                g_s[t] = Aa + Bb * rcp_hw(1.f + exp2_hw(K * acc));
            }
            __syncthreads();
            if (t < HID) {
                float ig=g_s[t], fg=g_s[HID+t], gg=g_s[2*HID+t], og=g_s[3*HID+t];
                c = fg*c + ig*gg;
                h_s[t] = og * tanh_hw(c);
            }
            __syncthreads();
        }
    }
    if (t < 16) {
        float a = fc1_b[t];
        #pragma unroll
        for (int j = 0; j < HID; ++j) a += h_s[j]*fc1_w[t*HID+j];
        g_s[t] = fmaxf(a, 0.f);
    }
    __syncthreads();
    if (t < NCLS) {
        float a = fc2_b[t];
        #pragma unroll
        for (int j = 0; j < 16; ++j) a += g_s[j]*fc2_w[t*16+j];
        out[b*NCLS + t] = a;
    }
}

extern "C" void kernel_launch(void* const* d_in, const int* in_sizes, int n_in,
                              void* d_out, int out_size, void* d_ws, size_t ws_size,
                              hipStream_t stream) {
    const float* x     = (const float*)d_in[0];
    const float* h0    = (const float*)d_in[1];
    const float* c0    = (const float*)d_in[2];
    const float* W_ih  = (const float*)d_in[3];
    const float* W_hh  = (const float*)d_in[4];
    const float* b_ih  = (const float*)d_in[5];
    const float* b_hh  = (const float*)d_in[6];
    const float* fc1_w = (const float*)d_in[7];
    const float* fc1_b = (const float*)d_in[8];
    const float* fc2_w = (const float*)d_in[9];
    const float* fc2_b = (const float*)d_in[10];
    float* out = (float*)d_out;

    // ---- primary: overlapped producer/consumer ----
    const size_t need = 4ull * (64 + (size_t)SS * BB * G4);
    if (ws_size >= need) {
        int*   flags = (int*)d_ws;
        float* xwbuf = (float*)d_ws + 64;
        init_flags<<<1, 64, 0, stream>>>(flags);
        lstm_pc2<<<NPROD + NCONS, 256, 0, stream>>>(x, h0, c0, W_ih, W_hh, b_ih, b_hh,
                                                    fc1_w, fc1_b, fc2_w, fc2_b, out,
                                                    flags, xwbuf);
        return;
    }

    // ---- fallback: serial chunked path ----
    const size_t state_floats = (size_t)BB * HID * 2;
    long cap = (long)(ws_size / 4) - (long)state_floats;
    long sc  = (cap > 0) ? cap / ((long)BB * G4) : 0;
    int  SC  = (int)((sc > SS) ? SS : sc) & ~15;

    if (SC < 16) {
        lstm_fused<<<BB, 192, 0, stream>>>(x, h0, c0, W_ih, W_hh, b_ih, b_hh,
                                           fc1_w, fc1_b, fc2_w, fc2_b, out);
        return;
    }

    float* state = (float*)d_ws;
    float* xwbuf = state + state_floats;

    for (int s0 = 0; s0 < SS; s0 += SC) {
        int cnt = SS - s0; if (cnt > SC) cnt = SC;
        int nseq = (cnt + 127) / 128;
        lstm_proj2<<<BB * nseq, 192, 0, stream>>>(x, W_ih, b_ih, b_hh, xwbuf, s0, cnt, nseq);
        lstm_recur<<<BB / 4, 256, 0, stream>>>(xwbuf, h0, c0, W_hh,
                                               fc1_w, fc1_b, fc2_w, fc2_b,
                                               state, out, s0, cnt);
    }
}

// Round 9
// 999.316 us; speedup vs baseline: 2.4341x; 2.4341x over previous
//
#include <hip/hip_runtime.h>
#include <hip/hip_bf16.h>

#define UNIT 20
#define HID 36
#define G4 144      // 4*HID
#define INW 80      // 4*UNIT
#define NCLS 3
#define TT 40960
#define SS 2048     // TT/UNIT
#define BB 512
#define PAD 16      // xw slop steps so recur prefetch needs no clamp

#define BFRAG_N 13824          // ushorts per half: 9n*3s*4g*16col*8j
#define BFRAG_BYTES 55296      // hi+lo

typedef float v2f  __attribute__((ext_vector_type(2)));
typedef short bf16x8 __attribute__((ext_vector_type(8)));
typedef float f32x4  __attribute__((ext_vector_type(4)));

__device__ __forceinline__ float exp2_hw(float x){ float r; asm("v_exp_f32 %0, %1" : "=v"(r) : "v"(x)); return r; }
__device__ __forceinline__ float rcp_hw(float x){ float r; asm("v_rcp_f32 %0, %1" : "=v"(r) : "v"(x)); return r; }
__device__ __forceinline__ float sigm_hw(float x){ return rcp_hw(1.f + exp2_hw(-1.4426950408889634f * x)); }
__device__ __forceinline__ float tanh_hw(float x){ return 1.f - 2.f * rcp_hw(1.f + exp2_hw(2.8853900817779268f * x)); }
__device__ __forceinline__ float rl(float v, int l){
    return __uint_as_float(__builtin_amdgcn_readlane(__float_as_uint(v), l));
}
__device__ __forceinline__ unsigned short f2bf(float f){
    unsigned int u = __float_as_uint(f);
    unsigned int r = (u + 0x7fffu + ((u >> 16) & 1u)) >> 16;   // RNE
    return (unsigned short)r;
}
__device__ __forceinline__ float bf2f(unsigned short h){
    return __uint_as_float(((unsigned int)h) << 16);
}

// ---------------- kernel 0: W_ih -> bf16 hi/lo B-fragments in ws ----------------
// B layout (ushort idx): ((n*3+s)*4+g)*128 + col*8 + j  ;  k = s*32+g*8+j, gate = n*16+col
__global__ __launch_bounds__(256)
void lstm_prep(const float* __restrict__ W_ih, unsigned short* __restrict__ B)
{
    int i = blockIdx.x * 256 + threadIdx.x;
    if (i >= BFRAG_N) return;
    int j   = i & 7;
    int col = (i >> 3) & 15;
    int gsl = i >> 7;
    int g   = gsl & 3;
    int ns  = gsl >> 2;
    int s   = ns % 3, n = ns / 3;
    int gate = n*16 + col;
    int k    = s*32 + g*8 + j;
    float v  = (k < 80) ? W_ih[(size_t)gate*INW + k] : 0.f;
    unsigned short h = f2bf(v);
    B[i]           = h;
    B[BFRAG_N + i] = f2bf(v - bf2f(h));
}

// ---------------- kernel 1: MFMA input projection ----------------
// 8192 blocks (512 b x 16 slabs of 128 steps), 256 thr = 4 waves, 2 M-tiles each.
// Per-wave LDS A buffer (no barriers). acc = Ahi*Bhi + Ahi*Blo + Alo*Bhi (~fp32).
__global__ __launch_bounds__(256)
void lstm_mproj(const float* __restrict__ x, const unsigned short* __restrict__ Bf,
                const float* __restrict__ b_ih, const float* __restrict__ b_hh,
                float* __restrict__ xw)
{
    const int bid = blockIdx.x;
    const int r   = bid & 15;        // 128-step slab
    const int b   = bid >> 4;
    const int tid = threadIdx.x;
    const int w   = tid >> 6;
    const int l   = tid & 63;
    const int col = l & 15;          // C col / A row / B col lane index
    const int g   = l >> 4;          // k-group

    __shared__ unsigned short A[4][2][16*104];   // per-wave [hi|lo], stride 104 (16B-aligned rows, 2-way banks)

    // zero the k=80..95 pad (tiles never overwrite it)
    for (int idx = l; idx < 256; idx += 64) {
        int s = idx >> 4, j = 80 + (idx & 15);
        A[w][0][s*104 + j] = 0;
        A[w][1][s*104 + j] = 0;
    }

    float bias[9];
    #pragma unroll
    for (int n = 0; n < 9; ++n) bias[n] = b_ih[n*16 + col] + b_hh[n*16 + col];

    const float* xb = x + (size_t)b * 4 * TT;
    const unsigned short* Blo = Bf + BFRAG_N;

    #pragma unroll
    for (int t = 0; t < 2; ++t) {
        const int sg0 = r*128 + w*32 + t*16;     // tile step base

        // ---- stage 16 steps of x as bf16 hi/lo into per-wave A ----
        #pragma unroll
        for (int i = 0; i < 5; ++i) {
            int f = i*64 + l;                    // 320 float4 = 16 steps x 80 floats
            int c = f / 80, rem = f - 80*c, s = rem / 5, q = rem - 5*s;
            float4 v = *(const float4*)(xb + (size_t)c*TT + (size_t)(sg0 + s)*UNIT + 4*q);
            int idx = s*104 + c*20 + 4*q;        // k = c*20+4q
            unsigned short h0 = f2bf(v.x), h1 = f2bf(v.y), h2 = f2bf(v.z), h3 = f2bf(v.w);
            ushort4 hh = {h0, h1, h2, h3};
            ushort4 ll = {f2bf(v.x - bf2f(h0)), f2bf(v.y - bf2f(h1)),
                          f2bf(v.z - bf2f(h2)), f2bf(v.w - bf2f(h3))};
            *(ushort4*)&A[w][0][idx] = hh;
            *(ushort4*)&A[w][1][idx] = ll;
        }
        // per-wave buffer: in-wave lgkmcnt ordering suffices, no barrier

        bf16x8 ah[3], al[3];
        #pragma unroll
        for (int s = 0; s < 3; ++s) {
            ah[s] = *(const bf16x8*)&A[w][0][col*104 + s*32 + g*8];   // row = col lane idx
            al[s] = *(const bf16x8*)&A[w][1][col*104 + s*32 + g*8];
        }

        #pragma unroll
        for (int n = 0; n < 9; ++n) {
            f32x4 acc = {bias[n], bias[n], bias[n], bias[n]};
            #pragma unroll
            for (int s = 0; s < 3; ++s) {
                const unsigned short* bp = Bf + ((n*3 + s)*4 + g)*128 + col*8;
                bf16x8 bh = *(const bf16x8*)bp;
                bf16x8 bl = *(const bf16x8*)(bp + BFRAG_N);
                acc = __builtin_amdgcn_mfma_f32_16x16x32_bf16(ah[s], bh, acc, 0, 0, 0);
                acc = __builtin_amdgcn_mfma_f32_16x16x32_bf16(ah[s], bl, acc, 0, 0, 0);
                acc = __builtin_amdgcn_mfma_f32_16x16x32_bf16(al[s], bh, acc, 0, 0, 0);
            }
            #pragma unroll
            for (int reg = 0; reg < 4; ++reg) {
                int step = sg0 + g*4 + reg;      // C: row=(l>>4)*4+reg, col=l&15  [m89]
                xw[((size_t)step * BB + b) * G4 + n*16 + col] = acc[reg];
            }
        }
    }
}

// ---------------- kernel 2: full-sequence recurrence (R7, proven) ----------------
__global__ __launch_bounds__(256)
void lstm_recur_full(const float* __restrict__ xw, const float* __restrict__ h0,
                     const float* __restrict__ c0, const float* __restrict__ W_hh,
                     const float* __restrict__ fc1_w, const float* __restrict__ fc1_b,
                     const float* __restrict__ fc2_w, const float* __restrict__ fc2_b,
                     float* __restrict__ out)
{
    const int wid  = threadIdx.x >> 6;
    const int lane = threadIdx.x & 63;
    const int b    = blockIdx.x * 4 + wid;
    const int jj   = (lane < HID) ? lane : 0;

    v2f wif[HID], wgo[HID];
    #pragma unroll
    for (int q = 0; q < HID; ++q) {
        wif[q] = (v2f){ W_hh[(size_t)jj*HID + q],         W_hh[(size_t)(HID+jj)*HID + q] };
        wgo[q] = (v2f){ W_hh[(size_t)(2*HID+jj)*HID + q], W_hh[(size_t)(3*HID+jj)*HID + q] };
    }

    float hval = h0[b*HID + jj];
    float cval = c0[b*HID + jj];
    float hs[HID];
    #pragma unroll
    for (int q = 0; q < HID; ++q) hs[q] = rl(hval, q);

    const float*  xp     = xw + (size_t)b * G4 + jj;
    const size_t  STRIDE = (size_t)BB * G4;

    float qa[8][4], qb[8][4];

#define LOADBANK(dst, base) { \
    _Pragma("unroll") for (int u = 0; u < 8; ++u) { \
        const float* p = xp + (size_t)((base) + u) * STRIDE; \
        dst[u][0] = p[0]; dst[u][1] = p[HID]; dst[u][2] = p[2*HID]; dst[u][3] = p[3*HID]; \
    } }

#define DOSTEP(bk, u) { \
    v2f aifA = { bk[u][0], bk[u][1] }, aifB = {0.f,0.f}; \
    v2f agoA = { bk[u][2], bk[u][3] }, agoB = {0.f,0.f}; \
    _Pragma("unroll") for (int q = 0; q < HID; q += 2) { \
        aifA += hs[q]   * wif[q]; \
        agoA += hs[q]   * wgo[q]; \
        aifB += hs[q+1] * wif[q+1]; \
        agoB += hs[q+1] * wgo[q+1]; \
    } \
    v2f aif = aifA + aifB, ago = agoA + agoB; \
    float gi = sigm_hw(aif[0]), gf = sigm_hw(aif[1]); \
    float gg = tanh_hw(ago[0]), go = sigm_hw(ago[1]); \
    cval = gf * cval + gi * gg; \
    hval = go * tanh_hw(cval); \
    _Pragma("unroll") for (int q = 0; q < HID; ++q) hs[q] = rl(hval, q); }

    LOADBANK(qa, 0);
    for (int s8 = 0; s8 < SS; s8 += 16) {
        LOADBANK(qb, s8 + 8);
        DOSTEP(qa,0) DOSTEP(qa,1) DOSTEP(qa,2) DOSTEP(qa,3)
        DOSTEP(qa,4) DOSTEP(qa,5) DOSTEP(qa,6) DOSTEP(qa,7)
        LOADBANK(qa, s8 + 16);                 // tail reads PAD slop
        DOSTEP(qb,0) DOSTEP(qb,1) DOSTEP(qb,2) DOSTEP(qb,3)
        DOSTEP(qb,4) DOSTEP(qb,5) DOSTEP(qb,6) DOSTEP(qb,7)
    }
#undef LOADBANK
#undef DOSTEP

    float a1 = 0.f;
    if (lane < 16) {
        a1 = fc1_b[lane];
        #pragma unroll
        for (int q = 0; q < HID; ++q) a1 += hs[q] * fc1_w[lane*HID + q];
        a1 = fmaxf(a1, 0.f);
    }
    float f1[16];
    #pragma unroll
    for (int q = 0; q < 16; ++q) f1[q] = rl(a1, q);
    if (lane < NCLS) {
        float a2 = fc2_b[lane];
        #pragma unroll
        for (int q = 0; q < 16; ++q) a2 += f1[q] * fc2_w[lane*16 + q];
        out[b*NCLS + lane] = a2;
    }
}

// ================= fallback serial path (R7 proven: proj2 + chunked recur) =================
__global__ __launch_bounds__(192)
void lstm_proj2(const float* __restrict__ x, const float* __restrict__ W_ih,
                const float* __restrict__ b_ih, const float* __restrict__ b_hh,
                float* __restrict__ xw, int s0, int cnt, int nseq)
{
    const int bid = blockIdx.x;
    const int r   = bid % nseq;
    const int b   = bid / nseq;
    const int t   = threadIdx.x;
    const int base_local = r * 128;
    const int mysteps = min(128, cnt - base_local);
    const bool act = (t < 144);
    const int pr   = act ? (t % 72) : 0;
    const int slot = act ? (t / 72) : 0;

    __shared__ __align__(16) float xin[16][INW];

    v2f wpk[INW]; v2f bias2 = {0.f, 0.f};
    if (act) {
        const float* w0 = W_ih + (size_t)pr * INW;
        const float* w1 = W_ih + (size_t)(pr + 72) * INW;
        #pragma unroll
        for (int q = 0; q < INW; ++q) wpk[q] = (v2f){w0[q], w1[q]};
        bias2 = (v2f){b_ih[pr] + b_hh[pr], b_ih[pr+72] + b_hh[pr+72]};
    }
    const float* xb = x + (size_t)b * 4 * TT;

    for (int sub = 0; sub < mysteps; sub += 16) {
        const int sg = s0 + base_local + sub;
        __syncthreads();
        for (int j = t; j < 320; j += 192) {
            int c = j / 80, q = j - c*80;
            float4 v = ((const float4*)(xb + (size_t)c*TT + (size_t)sg*UNIT))[q];
            int e = q*4; int sl = e / UNIT, u = e - sl*UNIT;
            *(float4*)&xin[sl][c*UNIT + u] = v;
        }
        __syncthreads();
        if (act) {
            for (int si = slot; si < 16; si += 2) {
                const float4* xv = (const float4*)xin[si];
                v2f a0 = bias2, a1 = {0.f,0.f}, a2 = {0.f,0.f}, a3 = {0.f,0.f};
                #pragma unroll
                for (int q = 0; q < 20; ++q) {
                    float4 v = xv[q];
                    a0 += v.x * wpk[4*q+0];
                    a1 += v.y * wpk[4*q+1];
                    a2 += v.z * wpk[4*q+2];
                    a3 += v.w * wpk[4*q+3];
                }
                v2f res = (a0 + a1) + (a2 + a3);
                size_t o = ((size_t)(base_local + sub + si) * BB + b) * G4;
                xw[o + pr]      = res[0];
                xw[o + pr + 72] = res[1];
            }
        }
    }
}

__global__ __launch_bounds__(256)
void lstm_recur(const float* __restrict__ xw, const float* __restrict__ h0,
                const float* __restrict__ c0, const float* __restrict__ W_hh,
                const float* __restrict__ fc1_w, const float* __restrict__ fc1_b,
                const float* __restrict__ fc2_w, const float* __restrict__ fc2_b,
                float* __restrict__ state, float* __restrict__ out, int s0, int cnt)
{
    const int wid  = threadIdx.x >> 6;
    const int lane = threadIdx.x & 63;
    const int b    = blockIdx.x * 4 + wid;
    const int jj   = (lane < HID) ? lane : 0;

    v2f wif[HID], wgo[HID];
    #pragma unroll
    for (int q = 0; q < HID; ++q) {
        wif[q] = (v2f){ W_hh[(size_t)jj*HID + q],         W_hh[(size_t)(HID+jj)*HID + q] };
        wgo[q] = (v2f){ W_hh[(size_t)(2*HID+jj)*HID + q], W_hh[(size_t)(3*HID+jj)*HID + q] };
    }

    float hval, cval;
    if (s0 == 0) { hval = h0[b*HID + jj];    cval = c0[b*HID + jj]; }
    else         { hval = state[b*HID + jj]; cval = state[BB*HID + b*HID + jj]; }

    float hs[HID];
    #pragma unroll
    for (int q = 0; q < HID; ++q) hs[q] = rl(hval, q);

    const float*  xp     = xw + (size_t)b * G4 + jj;
    const size_t  STRIDE = (size_t)BB * G4;

    float qa[8][4], qb[8][4];

#define LOADBANK(dst, base) { \
    _Pragma("unroll") for (int u = 0; u < 8; ++u) { \
        int ss = (base) + u; \
        const float* p = xp + (size_t)((ss < cnt) ? ss : 0) * STRIDE; \
        dst[u][0] = p[0]; dst[u][1] = p[HID]; dst[u][2] = p[2*HID]; dst[u][3] = p[3*HID]; \
    } }

#define DOSTEP(bk, u) { \
    v2f aifA = { bk[u][0], bk[u][1] }, aifB = {0.f,0.f}; \
    v2f agoA = { bk[u][2], bk[u][3] }, agoB = {0.f,0.f}; \
    _Pragma("unroll") for (int q = 0; q < HID; q += 2) { \
        aifA += hs[q]   * wif[q]; \
        agoA += hs[q]   * wgo[q]; \
        aifB += hs[q+1] * wif[q+1]; \
        agoB += hs[q+1] * wgo[q+1]; \
    } \
    v2f aif = aifA + aifB, ago = agoA + agoB; \
    float gi = sigm_hw(aif[0]), gf = sigm_hw(aif[1]); \
    float gg = tanh_hw(ago[0]), go = sigm_hw(ago[1]); \
    cval = gf * cval + gi * gg; \
    hval = go * tanh_hw(cval); \
    _Pragma("unroll") for (int q = 0; q < HID; ++q) hs[q] = rl(hval, q); }

    LOADBANK(qa, 0);
    for (int s8 = 0; s8 < cnt; s8 += 16) {
        LOADBANK(qb, s8 + 8);
        DOSTEP(qa,0) DOSTEP(qa,1) DOSTEP(qa,2) DOSTEP(qa,3)
        DOSTEP(qa,4) DOSTEP(qa,5) DOSTEP(qa,6) DOSTEP(qa,7)
        LOADBANK(qa, s8 + 16);
        DOSTEP(qb,0) DOSTEP(qb,1) DOSTEP(qb,2) DOSTEP(qb,3)
        DOSTEP(qb,4) DOSTEP(qb,5) DOSTEP(qb,6) DOSTEP(qb,7)
    }
#undef LOADBANK
#undef DOSTEP

    if (s0 + cnt == SS) {
        float a1 = 0.f;
        if (lane < 16) {
            a1 = fc1_b[lane];
            #pragma unroll
            for (int k = 0; k < HID; ++k) a1 += hs[k] * fc1_w[lane*HID + k];
            a1 = fmaxf(a1, 0.f);
        }
        float f1[16];
        #pragma unroll
        for (int k = 0; k < 16; ++k) f1[k] = rl(a1, k);
        if (lane < NCLS) {
            float a2 = fc2_b[lane];
            #pragma unroll
            for (int k = 0; k < 16; ++k) a2 += f1[k] * fc2_w[lane*16 + k];
            out[b*NCLS + lane] = a2;
        }
    } else {
        if (lane < HID) {
            state[b*HID + lane]          = hval;
            state[BB*HID + b*HID + lane] = cval;
        }
    }
}

// ---------------- ultimate fallback (R1 fused) ----------------
__global__ __launch_bounds__(192)
void lstm_fused(const float* __restrict__ x, const float* __restrict__ h0,
                const float* __restrict__ c0, const float* __restrict__ W_ih,
                const float* __restrict__ W_hh, const float* __restrict__ b_ih,
                const float* __restrict__ b_hh, const float* __restrict__ fc1_w,
                const float* __restrict__ fc1_b, const float* __restrict__ fc2_w,
                const float* __restrict__ fc2_b, float* __restrict__ out)
{
    const int b = blockIdx.x;
    const int t = threadIdx.x;
    __shared__ __align__(16) float xin[16][INW];
    __shared__ __align__(16) float xwl[16][G4];
    __shared__ __align__(16) float h_s[HID];
    __shared__ __align__(16) float g_s[G4];
    float wih[INW]; float whh[HID];
    float bias = 0.f, K = 0.f, Aa = 0.f, Bb = 0.f;
    if (t < G4) {
        const float4* wr = (const float4*)(W_ih + t * INW);
        #pragma unroll
        for (int i = 0; i < INW/4; ++i) { float4 v = wr[i]; wih[4*i]=v.x; wih[4*i+1]=v.y; wih[4*i+2]=v.z; wih[4*i+3]=v.w; }
        const float4* hr = (const float4*)(W_hh + t * HID);
        #pragma unroll
        for (int j = 0; j < HID/4; ++j) { float4 v = hr[j]; whh[4*j]=v.x; whh[4*j+1]=v.y; whh[4*j+2]=v.z; whh[4*j+3]=v.w; }
        bias = b_ih[t] + b_hh[t];
        const bool tnh = (t >= 2*HID && t < 3*HID);
        K  = tnh ?  2.8853900817779268f : -1.4426950408889634f;
        Aa = tnh ?  1.f : 0.f;
        Bb = tnh ? -2.f : 1.f;
    }
    float c = 0.f;
    if (t < HID) { c = c0[b*HID + t]; h_s[t] = h0[b*HID + t]; }
    __syncthreads();
    const float* xb = x + (size_t)b * 4 * TT;
    for (int ck = 0; ck < SS/16; ++ck) {
        const int base = ck * 16 * UNIT;
        for (int j = t; j < 4*16*UNIT; j += 192) {
            int chn = j / (16*UNIT); int r = j - chn*(16*UNIT);
            xin[r/UNIT][chn*UNIT + (r%UNIT)] = xb[chn*TT + base + r];
        }
        __syncthreads();
        if (t < G4) {
            for (int s = 0; s < 16; ++s) {
                const float4* xv = (const float4*)xin[s];
                float a0 = bias, a1 = 0.f, a2 = 0.f, a3 = 0.f;
                #pragma unroll
                for (int i = 0; i < INW/4; ++i) {
                    float4 v = xv[i];
                    a0 += v.x*wih[4*i]; a1 += v.y*wih[4*i+1]; a2 += v.z*wih[4*i+2]; a3 += v.w*wih[4*i+3];
                }
                xwl[s][t] = (a0+a1)+(a2+a3);
            }
        }
        __syncthreads();
        for (int s = 0; s < 16; ++s) {
            if (t < G4) {
                const float4* hv = (const float4*)h_s;
                float a0 = xwl[s][t], a1 = 0.f, a2 = 0.f, a3 = 0.f;
                #pragma unroll
                for (int j = 0; j < HID/4; ++j) {
                    float4 v = hv[j];
                    a0 += v.x*whh[4*j]; a1 += v.y*whh[4*j+1]; a2 += v.z*whh[4*j+2]; a3 += v.w*whh[4*j+3];
                }
                float acc = (a0+a1)+(a2+a3);
                g_s[t] = Aa + Bb * rcp_hw(1.f + exp2_hw(K * acc));
            }
            __syncthreads();
            if (t < HID) {
                float ig=g_s[t], fg=g_s[HID+t], gg=g_s[2*HID+t], og=g_s[3*HID+t];
                c = fg*c + ig*gg;
                h_s[t] = og * tanh_hw(c);
            }
            __syncthreads();
        }
    }
    if (t < 16) {
        float a = fc1_b[t];
        #pragma unroll
        for (int j = 0; j < HID; ++j) a += h_s[j]*fc1_w[t*HID+j];
        g_s[t] = fmaxf(a, 0.f);
    }
    __syncthreads();
    if (t < NCLS) {
        float a = fc2_b[t];
        #pragma unroll
        for (int j = 0; j < 16; ++j) a += g_s[j]*fc2_w[t*16+j];
        out[b*NCLS + t] = a;
    }
}

extern "C" void kernel_launch(void* const* d_in, const int* in_sizes, int n_in,
                              void* d_out, int out_size, void* d_ws, size_t ws_size,
                              hipStream_t stream) {
    const float* x     = (const float*)d_in[0];
    const float* h0    = (const float*)d_in[1];
    const float* c0    = (const float*)d_in[2];
    const float* W_ih  = (const float*)d_in[3];
    const float* W_hh  = (const float*)d_in[4];
    const float* b_ih  = (const float*)d_in[5];
    const float* b_hh  = (const float*)d_in[6];
    const float* fc1_w = (const float*)d_in[7];
    const float* fc1_b = (const float*)d_in[8];
    const float* fc2_w = (const float*)d_in[9];
    const float* fc2_b = (const float*)d_in[10];
    float* out = (float*)d_out;

    // ---- primary: MFMA proj + full-sequence recurrence ----
    // ws layout: [B frags hi/lo 55296 B][xw (SS+PAD)*BB*G4 f32]
    const size_t need = BFRAG_BYTES + 4ull * (size_t)(SS + PAD) * BB * G4;
    if (ws_size >= need) {
        unsigned short* Bf = (unsigned short*)d_ws;
        float* xwbuf = (float*)((char*)d_ws + BFRAG_BYTES);
        lstm_prep <<<(BFRAG_N + 255)/256, 256, 0, stream>>>(W_ih, Bf);
        lstm_mproj<<<BB * (SS/128), 256, 0, stream>>>(x, Bf, b_ih, b_hh, xwbuf);
        lstm_recur_full<<<BB / 4, 256, 0, stream>>>(xwbuf, h0, c0, W_hh,
                                                    fc1_w, fc1_b, fc2_w, fc2_b, out);
        return;
    }

    // ---- fallback: chunked fp32 path (R7 proven) ----
    const size_t state_floats = (size_t)BB * HID * 2;
    long cap = (long)(ws_size / 4) - (long)state_floats;
    long sc  = (cap > 0) ? cap / ((long)BB * G4) : 0;
    int  SC  = (int)((sc > SS) ? SS : sc) & ~15;

    if (SC < 16) {
        lstm_fused<<<BB, 192, 0, stream>>>(x, h0, c0, W_ih, W_hh, b_ih, b_hh,
                                           fc1_w, fc1_b, fc2_w, fc2_b, out);
        return;
    }

    float* state = (float*)d_ws;
    float* xwbuf = state + state_floats;

    for (int s0 = 0; s0 < SS; s0 += SC) {
        int cnt = SS - s0; if (cnt > SC) cnt = SC;
        int nseq = (cnt + 127) / 128;
        lstm_proj2<<<BB * nseq, 192, 0, stream>>>(x, W_ih, b_ih, b_hh, xwbuf, s0, cnt, nseq);
        lstm_recur<<<BB / 4, 256, 0, stream>>>(xwbuf, h0, c0, W_hh,
                                               fc1_w, fc1_b, fc2_w, fc2_b,
                                               state, out, s0, cnt);
    }
}